// Round 5
// baseline (643.471 us; speedup 1.0000x reference)
//
#include <hip/hip_runtime.h>
#include <hip/hip_cooperative_groups.h>

namespace cg = cooperative_groups;

#define NPIX (1024 * 1024)
#define NBATCH 16
#define NBINS 8192
#define GRID 512
#define THREADS 512
#define SUBPB (GRID / NBATCH)   // 32 blocks per batch
#define PIXPB (NPIX / SUBPB)    // 32768 pixels per block

typedef float vfloat4 __attribute__((ext_vector_type(4)));

// ---------------------------------------------------------------------------
// ONE cooperative kernel: zero -> sync -> hist -> sync -> scan -> sync ->
// apply. Rationale (R4 post-mortem): 4 rounds of structural variation all
// land at ~385 us; the only dispatches big enough to show counters are the
// harness poison fills. Fusing makes our entire pipeline ONE dispatch that
// (a) removes 2-3 launch boundaries / grid drains, (b) is >120 us so rocprof
// finally shows us FETCH/WRITE/VALUBusy for our own code.
// 512 blocks x 512 threads = 2 blocks/CU (34.3KB LDS, low VGPR -> cooperative
// co-residency guaranteed; R3 vs R4 showed hist occupancy doesn't matter).
// ---------------------------------------------------------------------------
__global__ __launch_bounds__(THREADS) void fused_kernel(
        const float* __restrict__ img,
        const float* __restrict__ rgb2yuv,
        unsigned int* __restrict__ ghist,
        float* __restrict__ stats,
        float* __restrict__ out) {
    __shared__ unsigned int lh[NBINS];
    __shared__ unsigned int segsum[THREADS];
    __shared__ float vals[4];

    cg::grid_group grid = cg::this_grid();
    const int t = threadIdx.x;
    const int blk = blockIdx.x;
    const int b = blk / SUBPB;  // batch
    const int s = blk % SUBPB;  // sub-block within batch

    // ---- P0: zero the 16 global histograms + this block's LDS hist ----
    {
        int gtid = blk * THREADS + t;
        if (gtid < NBATCH * NBINS) ghist[gtid] = 0u;
        for (int i = t; i < NBINS; i += THREADS) lh[i] = 0u;
    }
    const float c0 = rgb2yuv[0];
    const float c1 = rgb2yuv[1];
    const float c2 = rgb2yuv[2];
    grid.sync();

    // ---- P1: LDS histogram of luminance, global-atomic flush ----
    {
        const size_t base = (size_t)b * 3 * NPIX + (size_t)s * PIXPB;
        const float4* r4 = (const float4*)(img + base);
        const float4* g4 = (const float4*)(img + base + NPIX);
        const float4* b4 = (const float4*)(img + base + 2 * (size_t)NPIX);
        const int n4 = PIXPB / 4;  // 8192
        const float scale = (float)NBINS;

        for (int i = t; i < n4; i += 2 * THREADS) {
            float4 R0 = r4[i];
            float4 R1 = r4[i + THREADS];
            float4 G0 = g4[i];
            float4 G1 = g4[i + THREADS];
            float4 B0 = b4[i];
            float4 B1 = b4[i + THREADS];

            float y0 = c0 * R0.x + c1 * G0.x + c2 * B0.x;
            float y1 = c0 * R0.y + c1 * G0.y + c2 * B0.y;
            float y2 = c0 * R0.z + c1 * G0.z + c2 * B0.z;
            float y3 = c0 * R0.w + c1 * G0.w + c2 * B0.w;
            float y4 = c0 * R1.x + c1 * G1.x + c2 * B1.x;
            float y5 = c0 * R1.y + c1 * G1.y + c2 * B1.y;
            float y6 = c0 * R1.z + c1 * G1.z + c2 * B1.z;
            float y7 = c0 * R1.w + c1 * G1.w + c2 * B1.w;

            int i0 = min(NBINS - 1, max(0, (int)(y0 * scale)));
            int i1 = min(NBINS - 1, max(0, (int)(y1 * scale)));
            int i2 = min(NBINS - 1, max(0, (int)(y2 * scale)));
            int i3 = min(NBINS - 1, max(0, (int)(y3 * scale)));
            int i4 = min(NBINS - 1, max(0, (int)(y4 * scale)));
            int i5 = min(NBINS - 1, max(0, (int)(y5 * scale)));
            int i6 = min(NBINS - 1, max(0, (int)(y6 * scale)));
            int i7 = min(NBINS - 1, max(0, (int)(y7 * scale)));

            atomicAdd(&lh[i0], 1u);
            atomicAdd(&lh[i1], 1u);
            atomicAdd(&lh[i2], 1u);
            atomicAdd(&lh[i3], 1u);
            atomicAdd(&lh[i4], 1u);
            atomicAdd(&lh[i5], 1u);
            atomicAdd(&lh[i6], 1u);
            atomicAdd(&lh[i7], 1u);
        }
        __syncthreads();

        unsigned int* dst = ghist + (size_t)b * NBINS;
        for (int i = t; i < NBINS; i += THREADS) {
            unsigned int v = lh[i];
            if (v) atomicAdd(&dst[i], v);
        }
        __threadfence();
    }
    grid.sync();

    // ---- P2: blocks 0..15 scan their batch's completed histogram ----
    if (blk < NBATCH) {
        const uint4* gh = (const uint4*)(ghist + (size_t)blk * NBINS);
        uint4* lh4 = (uint4*)lh;
        unsigned int ss = 0;
#pragma unroll
        for (int k = 0; k < 4; ++k) {  // thread t owns bins [16t, 16t+16)
            uint4 h = gh[t * 4 + k];
            lh4[t * 4 + k] = h;
            ss += h.x + h.y + h.z + h.w;
        }
        segsum[t] = ss;
        __syncthreads();

        for (int off = 1; off < THREADS; off <<= 1) {
            unsigned int v = segsum[t];
            unsigned int add = (t >= off) ? segsum[t - off] : 0u;
            __syncthreads();
            segsum[t] = v + add;
            __syncthreads();
        }

        const unsigned int cumincl = segsum[t];
        const unsigned int cumbefore = (t > 0) ? segsum[t - 1] : 0u;

        const unsigned int ranks[4] = {10485u, 10486u, 1038089u, 1038090u};
        const int BPT = NBINS / THREADS;  // 16
#pragma unroll
        for (int q = 0; q < 4; ++q) {
            unsigned int r = ranks[q];
            if (r >= cumbefore && r < cumincl) {
                unsigned int running = cumbefore;
                for (int j = 0; j < BPT; ++j) {
                    unsigned int c = lh[t * BPT + j];
                    if (r < running + c) {
                        vals[q] = ((float)(t * BPT + j) +
                                   ((float)(r - running) + 0.5f) / (float)c) *
                                  (1.0f / (float)NBINS);
                        break;
                    }
                    running += c;
                }
            }
        }
        __syncthreads();

        if (t == 0) {
            float blkp = 0.25f * vals[0] + 0.75f * vals[1];
            float wht = 0.75f * vals[2] + 0.25f * vals[3];
            float mult = fminf(1.0f / (wht - blkp), 1.5f);
            stats[blk * 2 + 0] = blkp;
            stats[blk * 2 + 1] = mult;
        }
        __threadfence();
    }
    grid.sync();

    // ---- P3: apply. Same (b, s) ownership as hist -> img chunk is L2/L3
    // warm from P1 on this very XCD. ----
    {
        const float blkp = stats[b * 2 + 0];
        const float mult = stats[b * 2 + 1];
        const int n = 3 * PIXPB / 4;  // 24576 vfloat4 per block
        const vfloat4* in4 =
            (const vfloat4*)(img + (size_t)b * 3 * NPIX) + (size_t)s * n;
        vfloat4* o4 = (vfloat4*)(out + (size_t)b * 3 * NPIX) + (size_t)s * n;

#pragma unroll 4
        for (int i = t; i < n; i += THREADS) {
            vfloat4 v = in4[i];
            v.x = fminf(fmaxf((v.x - blkp) * mult, 0.0f), 1.0f);
            v.y = fminf(fmaxf((v.y - blkp) * mult, 0.0f), 1.0f);
            v.z = fminf(fmaxf((v.z - blkp) * mult, 0.0f), 1.0f);
            v.w = fminf(fmaxf((v.w - blkp) * mult, 0.0f), 1.0f);
            o4[i] = v;
        }
    }
}

extern "C" void kernel_launch(void* const* d_in, const int* in_sizes, int n_in,
                              void* d_out, int out_size, void* d_ws, size_t ws_size,
                              hipStream_t stream) {
    const float* img = (const float*)d_in[0];
    const float* rgb2yuv = (const float*)d_in[1];
    float* out = (float*)d_out;

    // Workspace layout: [0,128): stats (16 * {blk, mult});
    // [256, 256 + 512K): ghist (16 batches x 8192 bins, u32).
    float* stats = (float*)d_ws;
    unsigned int* ghist = (unsigned int*)((char*)d_ws + 256);

    void* args[] = {(void*)&img, (void*)&rgb2yuv, (void*)&ghist, (void*)&stats,
                    (void*)&out};
    hipLaunchCooperativeKernel((void*)fused_kernel, dim3(GRID), dim3(THREADS),
                               args, 0, stream);
}

// Round 6
// 375.058 us; speedup vs baseline: 1.7157x; 1.7157x over previous
//
#include <hip/hip_runtime.h>

#define NPIX (1024 * 1024)
#define NBATCH 16
#define NBINS 8192
#define SUBPB 64                 // hist blocks per batch
#define HTHREADS 512
#define PIXPB (NPIX / SUBPB)     // 16384 pixels per hist block

typedef float vfloat4 __attribute__((ext_vector_type(4)));

// ---------------------------------------------------------------------------
// Kernel 0: zero the 16 per-batch histograms (512 KB). ~2 us (R0-measured).
// ---------------------------------------------------------------------------
__global__ void zero_kernel(unsigned int* __restrict__ g) {
    int i = blockIdx.x * blockDim.x + threadIdx.x;
    int n = NBATCH * NBINS;
    for (; i < n; i += gridDim.x * blockDim.x) g[i] = 0u;
}

// ---------------------------------------------------------------------------
// Kernel 1: LDS histogram with a 2-AHEAD SOFTWARE PIPELINE.
// R5 post-mortem: hist is stuck at ~2.5 TB/s with VALUBusy 2%, occupancy
// maxed, LDS conflicts trivial -> remaining theory is the per-iteration
// vmcnt drain (loads consumed immediately; zero loads in flight across the
// loop back-edge). Here iter k+2's 3 float4 loads are issued BEFORE iter
// k's compute+atomics, keeping 6 loads/lane in flight continuously.
// 1024 blocks x 512 thr = 4 blocks/CU x 8 waves = 32 waves/CU.
// Flush: global atomics into per-batch hist (R0<->R1 A/B: free).
// ---------------------------------------------------------------------------
__global__ __launch_bounds__(HTHREADS) void hist_kernel(
        const float* __restrict__ img,
        const float* __restrict__ rgb2yuv,
        unsigned int* __restrict__ ghist) {
    __shared__ unsigned int lh[NBINS];
    for (int i = threadIdx.x; i < NBINS; i += HTHREADS) lh[i] = 0;
    const float c0 = rgb2yuv[0];
    const float c1 = rgb2yuv[1];
    const float c2 = rgb2yuv[2];
    __syncthreads();

    const int b = blockIdx.x / SUBPB;
    const int s = blockIdx.x % SUBPB;
    const size_t base = (size_t)b * 3 * NPIX + (size_t)s * PIXPB;

    const float4* r4 = (const float4*)(img + base);
    const float4* g4 = (const float4*)(img + base + NPIX);
    const float4* b4 = (const float4*)(img + base + 2 * (size_t)NPIX);
    // PIXPB/4 = 4096 float4 triples; 8 iterations of HTHREADS
    const int t = threadIdx.x;
    const float scale = (float)NBINS;

    // Pipeline prologue: 2 stages in flight.
    float4 Ra = r4[t], Ga = g4[t], Ba = b4[t];
    float4 Rb = r4[t + HTHREADS], Gb = g4[t + HTHREADS], Bb = b4[t + HTHREADS];

#pragma unroll
    for (int k = 0; k < 8; ++k) {
        float4 Rc = {0.f, 0.f, 0.f, 0.f};
        float4 Gc = {0.f, 0.f, 0.f, 0.f};
        float4 Bc = {0.f, 0.f, 0.f, 0.f};
        if (k + 2 < 8) {
            int j = t + (k + 2) * HTHREADS;
            Rc = r4[j];
            Gc = g4[j];
            Bc = b4[j];
        }
        // Compute + LDS atomics on stage A (loads issued 2 iterations ago).
        float y0 = c0 * Ra.x + c1 * Ga.x + c2 * Ba.x;
        float y1 = c0 * Ra.y + c1 * Ga.y + c2 * Ba.y;
        float y2 = c0 * Ra.z + c1 * Ga.z + c2 * Ba.z;
        float y3 = c0 * Ra.w + c1 * Ga.w + c2 * Ba.w;
        int i0 = min(NBINS - 1, max(0, (int)(y0 * scale)));
        int i1 = min(NBINS - 1, max(0, (int)(y1 * scale)));
        int i2 = min(NBINS - 1, max(0, (int)(y2 * scale)));
        int i3 = min(NBINS - 1, max(0, (int)(y3 * scale)));
        atomicAdd(&lh[i0], 1u);
        atomicAdd(&lh[i1], 1u);
        atomicAdd(&lh[i2], 1u);
        atomicAdd(&lh[i3], 1u);
        // Rotate pipeline.
        Ra = Rb; Ga = Gb; Ba = Bb;
        Rb = Rc; Gb = Gc; Bb = Bc;
    }
    __syncthreads();

    // Global atomic flush into the per-batch histogram (measured free).
    unsigned int* dst = ghist + (size_t)b * NBINS;
    for (int i = t; i < NBINS; i += HTHREADS) {
        unsigned int v = lh[i];
        if (v) atomicAdd(&dst[i], v);
    }
}

// ---------------------------------------------------------------------------
// Kernel 2: one block per batch, reads the FINAL 32 KB histogram directly
// (no sub-hist reduction), scans, locates the 4 order statistics
// (10485,10486 / 1038089,1038090), interpolates, writes (blkpt, mult).
// R0-measured structure.
// ---------------------------------------------------------------------------
__global__ __launch_bounds__(1024) void scan_kernel(
        const unsigned int* __restrict__ ghist,
        float* __restrict__ stats) {
    __shared__ unsigned int hist[NBINS];
    __shared__ unsigned int segsum[1024];
    __shared__ float vals[4];

    const int b = blockIdx.x;
    const int t = threadIdx.x;

    for (int i = t; i < NBINS; i += 1024)
        hist[i] = ghist[(size_t)b * NBINS + i];
    __syncthreads();

    const int BPT = NBINS / 1024;  // 8
    unsigned int ss = 0;
#pragma unroll
    for (int j = 0; j < BPT; ++j) ss += hist[t * BPT + j];
    segsum[t] = ss;
    __syncthreads();

    for (int off = 1; off < 1024; off <<= 1) {
        unsigned int v = segsum[t];
        unsigned int add = (t >= off) ? segsum[t - off] : 0u;
        __syncthreads();
        segsum[t] = v + add;
        __syncthreads();
    }

    const unsigned int cumincl = segsum[t];
    const unsigned int cumbefore = (t > 0) ? segsum[t - 1] : 0u;

    const unsigned int ranks[4] = {10485u, 10486u, 1038089u, 1038090u};
#pragma unroll
    for (int q = 0; q < 4; ++q) {
        unsigned int r = ranks[q];
        if (r >= cumbefore && r < cumincl) {
            unsigned int running = cumbefore;
#pragma unroll
            for (int j = 0; j < BPT; ++j) {
                unsigned int c = hist[t * BPT + j];
                if (r < running + c) {
                    vals[q] = ((float)(t * BPT + j) +
                               ((float)(r - running) + 0.5f) / (float)c) *
                              (1.0f / (float)NBINS);
                    break;
                }
                running += c;
            }
        }
    }
    __syncthreads();

    if (t == 0) {
        float blk = 0.25f * vals[0] + 0.75f * vals[1];
        float wht = 0.75f * vals[2] + 0.25f * vals[3];
        float mult = fminf(1.0f / (wht - blk), 1.5f);
        stats[b * 2 + 0] = blk;
        stats[b * 2 + 1] = mult;
    }
}

// ---------------------------------------------------------------------------
// Kernel 3: out = clip((img - blk[b]) * mult[b], 0, 1). ~51 us inferred
// (near roofline: 201 MB write + L3-warm read). Plain stores (R4 A/B:
// NT == plain). 12288 blocks x 256 thr, 4 float4/thread.
// ---------------------------------------------------------------------------
__global__ __launch_bounds__(256) void apply_kernel(
        const float* __restrict__ img,
        const float* __restrict__ stats,
        float* __restrict__ out) {
    const int blocksPerBatch = (3 * NPIX / 4) / 1024;  // 768
    const int b = blockIdx.x / blocksPerBatch;
    const int c = blockIdx.x % blocksPerBatch;
    const float blk = stats[b * 2 + 0];
    const float mult = stats[b * 2 + 1];

    const vfloat4* in4 =
        (const vfloat4*)(img + (size_t)b * 3 * NPIX) + (size_t)c * 1024;
    vfloat4* out4 = (vfloat4*)(out + (size_t)b * 3 * NPIX) + (size_t)c * 1024;

    const int t = threadIdx.x;
    vfloat4 v0 = in4[t];
    vfloat4 v1 = in4[t + 256];
    vfloat4 v2 = in4[t + 512];
    vfloat4 v3 = in4[t + 768];

#define CLIP1(vv)                                          \
    vv.x = fminf(fmaxf((vv.x - blk) * mult, 0.0f), 1.0f);  \
    vv.y = fminf(fmaxf((vv.y - blk) * mult, 0.0f), 1.0f);  \
    vv.z = fminf(fmaxf((vv.z - blk) * mult, 0.0f), 1.0f);  \
    vv.w = fminf(fmaxf((vv.w - blk) * mult, 0.0f), 1.0f)
    CLIP1(v0);
    CLIP1(v1);
    CLIP1(v2);
    CLIP1(v3);
#undef CLIP1

    out4[t] = v0;
    out4[t + 256] = v1;
    out4[t + 512] = v2;
    out4[t + 768] = v3;
}

extern "C" void kernel_launch(void* const* d_in, const int* in_sizes, int n_in,
                              void* d_out, int out_size, void* d_ws, size_t ws_size,
                              hipStream_t stream) {
    const float* img = (const float*)d_in[0];
    const float* rgb2yuv = (const float*)d_in[1];
    float* out = (float*)d_out;

    // Workspace layout: [0,128): stats (16 * {blk, mult});
    // [256, 256 + 512K): ghist (16 batches x 8192 bins, u32).
    float* stats = (float*)d_ws;
    unsigned int* ghist = (unsigned int*)((char*)d_ws + 256);

    zero_kernel<<<128, 256, 0, stream>>>(ghist);
    hist_kernel<<<NBATCH * SUBPB, HTHREADS, 0, stream>>>(img, rgb2yuv, ghist);
    scan_kernel<<<NBATCH, 1024, 0, stream>>>(ghist, stats);

    const int applyBlocks = NBATCH * ((3 * NPIX / 4) / 1024);  // 12288
    apply_kernel<<<applyBlocks, 256, 0, stream>>>(img, stats, out);
}